// Round 5
// baseline (150.619 us; speedup 1.0000x reference)
//
#include <hip/hip_runtime.h>
#include <hip/hip_bf16.h>
#include <math.h>

typedef __bf16 bf16x8 __attribute__((ext_vector_type(8)));
typedef __bf16 bf16x4 __attribute__((ext_vector_type(4)));
typedef float  f32x4  __attribute__((ext_vector_type(4)));

constexpr int EMBED = 1024;
constexpr int NH    = 16;
constexpr int HD    = 64;
constexpr int LL    = 2048;
constexpr int BB    = 2;
constexpr int SSEQ  = 2048;

constexpr int BQ = 128;         // q rows per block (4 waves x 32)
constexpr int BK = 64;          // kv rows per tile
constexpr int NT = SSEQ / BK;   // 32 tiles

// Workspace: K bf16 [b][h][s][d] (8 MiB) then V^T bf16 [b][h][d][s] (8 MiB)
constexpr size_t KW_ELEMS = (size_t)BB * NH * SSEQ * HD;

__device__ __forceinline__ void gload16(const void* g, void* l) {
  __builtin_amdgcn_global_load_lds((const __attribute__((address_space(1))) unsigned int*)g,
                                   (__attribute__((address_space(3))) unsigned int*)l, 16, 0, 0);
}

__device__ __forceinline__ float exp2_fast(float x) {
  float r;
  asm("v_exp_f32 %0, %1" : "=v"(r) : "v"(x));
  return r;
}

// ---- prepass: K -> bf16 [b][h][s][d]; V -> bf16 transposed [b][h][d][s] ----
__global__ __launch_bounds__(256) void prep_kv(const float* __restrict__ Kg,
                                               const float* __restrict__ Vg,
                                               __hip_bfloat16* __restrict__ kw,
                                               __hip_bfloat16* __restrict__ vtw) {
  __shared__ char tsh[64 * 128];
  const int bid = blockIdx.x;
  if (bid < 2048) {
    const int idx = bid * 256 + threadIdx.x;
    const int e8 = idx & 127;
    const int t2 = idx >> 7;
    const int b  = t2 & 1;
    const int s  = t2 >> 1;
    const int h  = e8 >> 3;
    const int d8 = e8 & 7;
    const float* src = Kg + ((size_t)s * BB + b) * EMBED + e8 * 8;
    float4 a = *(const float4*)src;
    float4 c = *(const float4*)(src + 4);
    bf16x8 w;
    w[0] = (__bf16)a.x; w[1] = (__bf16)a.y; w[2] = (__bf16)a.z; w[3] = (__bf16)a.w;
    w[4] = (__bf16)c.x; w[5] = (__bf16)c.y; w[6] = (__bf16)c.z; w[7] = (__bf16)c.w;
    *(bf16x8*)(kw + (((size_t)(b * NH + h) * SSEQ + s) * HD + d8 * 8)) = w;
  } else {
    const int vb2 = bid - 2048;
    const int st  = vb2 & 31;
    const int bh  = vb2 >> 5;
    const int b   = bh >> 4;
    const int h   = bh & 15;
    const int t   = threadIdx.x;
    {
      const int r  = t >> 2;
      const int c0 = (t & 3) * 16;
      const float* src = Vg + ((size_t)(st * 64 + r) * BB + b) * EMBED + h * HD + c0;
      float4 x0 = *(const float4*)(src);
      float4 x1 = *(const float4*)(src + 4);
      float4 x2 = *(const float4*)(src + 8);
      float4 x3 = *(const float4*)(src + 12);
      bf16x8 w0, w1;
      w0[0] = (__bf16)x0.x; w0[1] = (__bf16)x0.y; w0[2] = (__bf16)x0.z; w0[3] = (__bf16)x0.w;
      w0[4] = (__bf16)x1.x; w0[5] = (__bf16)x1.y; w0[6] = (__bf16)x1.z; w0[7] = (__bf16)x1.w;
      w1[0] = (__bf16)x2.x; w1[1] = (__bf16)x2.y; w1[2] = (__bf16)x2.z; w1[3] = (__bf16)x2.w;
      w1[4] = (__bf16)x3.x; w1[5] = (__bf16)x3.y; w1[6] = (__bf16)x3.z; w1[7] = (__bf16)x3.w;
      const int colb = ((c0 + (r >> 3) * 16) & 63) * 2;
      char* rowp = tsh + r * 128;
      *(bf16x8*)(rowp + colb)      = w0;
      *(bf16x8*)(rowp + colb + 16) = w1;
    }
    __syncthreads();
    {
      const int d   = t >> 2;
      const int sc0 = (t & 3) * 16;
      bf16x8 o0, o1;
#pragma unroll
      for (int i = 0; i < 8; ++i) {
        const int s = sc0 + i;
        o0[i] = *(const __bf16*)(tsh + s * 128 + (((d + (s >> 3) * 16) & 63) * 2));
      }
#pragma unroll
      for (int i = 8; i < 16; ++i) {
        const int s = sc0 + i;
        o1[i - 8] = *(const __bf16*)(tsh + s * 128 + (((d + (s >> 3) * 16) & 63) * 2));
      }
      __hip_bfloat16* dst = vtw + ((size_t)(bh * HD + d)) * SSEQ + st * 64 + sc0;
      *(bf16x8*)(dst)     = o0;
      *(bf16x8*)(dst + 8) = o1;
    }
  }
}

// ---- hot kernel: flash attention, 4 waves x 32 q-rows, BQ=128 ----
__global__ __launch_bounds__(256) void sdpa_fwd(const float* __restrict__ Qg,
                                                const __hip_bfloat16* __restrict__ Kw,
                                                const __hip_bfloat16* __restrict__ VTw,
                                                float* __restrict__ Og) {
  __shared__ char sh[49152];
  char* kbuf = sh;            // [2][8192] K tile
  char* vbuf = sh + 16384;    // [2][8192] V^T tile
  char* psh  = sh + 32768;    // [4][4096] per-wave P tiles (A,B halves)

  const int tid  = threadIdx.x;
  const int wv   = tid >> 6;
  const int lane = tid & 63;
  const int g    = lane >> 4;
  const int qc   = lane & 15;

  // XCD-clustered decode: all 16 q-blocks of a head land on one XCD.
  const int bid = blockIdx.x;
  const int xcd = bid & 7;
  const int rest = bid >> 3;
  const int qb  = rest & 15;
  const int bh  = ((rest >> 4) << 3) | xcd;
  const int bb  = bh >> 4;
  const int hh  = bh & 15;

  const size_t rstride = (size_t)BB * EMBED;
  const float* qb_ptr = Qg + (size_t)bb * EMBED + hh * HD;
  float*       ob     = Og + (size_t)bb * EMBED + hh * HD;
  const char*  kwb = (const char*)(Kw + (size_t)bh * SSEQ * HD);
  const char*  vtb = (const char*)(VTw + (size_t)bh * HD * SSEQ);

  const int qrow0 = qb * BQ + wv * 32;   // wave covers 32 q rows (A: +0, B: +16)

  // staging: wave wv covers tile rows wv*16 .. wv*16+15 (two 8-row gloads)
  const int rW0 = wv * 16 + (lane >> 3);       // rows +0..7
  const int cW  = (lane & 7) ^ (rW0 & 7);      // inverse swizzle ((rW0+8)&7 == rW0&7)
  const char* kg0 = kwb + rW0 * 128 + cW * 16;              // +8192/tile; +1024 for rows 8..15
  const char* vg0 = vtb + (size_t)rW0 * 4096 + cW * 16;     // +128/tile;  +8*4096 for rows 8..15
  char* kdS = kbuf + wv * 2048;                // wave-uniform LDS bases
  char* vdS = vbuf + wv * 2048;

#define STAGE(B, T)                                                 \
  do {                                                              \
    gload16(kg0 + (size_t)(T) * 8192,        kdS + (B) * 8192);     \
    gload16(kg0 + (size_t)(T) * 8192 + 1024, kdS + (B) * 8192 + 1024); \
    gload16(vg0 + (size_t)(T) * 128,             vdS + (B) * 8192);     \
    gload16(vg0 + (size_t)(T) * 128 + 8 * 4096,  vdS + (B) * 8192 + 1024); \
  } while (0)

  // ---- Q fragments for both halves; scale folds 1/8 * log2(e) ----
  constexpr float QSC = 0.125f * 1.4426950408889634f;
  bf16x8 qfA[2], qfB[2];
  {
#pragma unroll
    for (int h2 = 0; h2 < 2; ++h2) {
      const float* qr = qb_ptr + (size_t)(qrow0 + h2 * 16 + qc) * rstride;
#pragma unroll
      for (int f = 0; f < 2; ++f) {
        const float* p = qr + f * 32 + g * 8;
        float4 a = *(const float4*)p;
        float4 c = *(const float4*)(p + 4);
        bf16x8 w;
        w[0] = (__bf16)(a.x * QSC); w[1] = (__bf16)(a.y * QSC);
        w[2] = (__bf16)(a.z * QSC); w[3] = (__bf16)(a.w * QSC);
        w[4] = (__bf16)(c.x * QSC); w[5] = (__bf16)(c.y * QSC);
        w[6] = (__bf16)(c.z * QSC); w[7] = (__bf16)(c.w * QSC);
        if (h2 == 0) qfA[f] = w; else qfB[f] = w;
      }
    }
  }

  f32x4 accA[4], accB[4];
#pragma unroll
  for (int nb = 0; nb < 4; ++nb) {
    accA[nb][0] = 0.f; accA[nb][1] = 0.f; accA[nb][2] = 0.f; accA[nb][3] = 0.f;
    accB[nb][0] = 0.f; accB[nb][1] = 0.f; accB[nb][2] = 0.f; accB[nb][3] = 0.f;
  }
  float mA = -INFINITY, lA = 0.f;
  float mB = -INFINITY, lB = 0.f;

  const int sw = (qc & 7) << 4;
  char* pwA = psh + wv * 4096;
  char* pwB = pwA + 2048;

  // softmax + P-pack for one half (st in log2 units; pack into PW)
#define SOFTMAX_PACK(ST, M, LSUM, ACC, PW)                                    \
  do {                                                                        \
    float mx = fmaxf(fmaxf(fmaxf(ST[0][0], ST[0][1]), ST[0][2]),              \
                     fmaxf(fmaxf(ST[0][3], ST[1][0]), ST[1][1]));             \
    mx = fmaxf(mx, fmaxf(fmaxf(ST[1][2], ST[1][3]), ST[2][0]));               \
    mx = fmaxf(mx, fmaxf(fmaxf(ST[2][1], ST[2][2]), ST[2][3]));               \
    mx = fmaxf(mx, fmaxf(fmaxf(ST[3][0], ST[3][1]),                           \
                         fmaxf(ST[3][2], ST[3][3])));                         \
    mx = fmaxf(mx, __shfl_xor(mx, 16));                                       \
    mx = fmaxf(mx, __shfl_xor(mx, 32));                                       \
    if (!__all(mx - M <= 8.0f)) {                                             \
      const float mnew  = fmaxf(M, mx);                                       \
      const float alpha = exp2_fast(M - mnew);                                \
      M = mnew;                                                               \
      LSUM *= alpha;                                                          \
      float ar[4];                                                            \
      _Pragma("unroll")                                                       \
      for (int r2 = 0; r2 < 4; ++r2) ar[r2] = __shfl(alpha, g * 4 + r2);      \
      _Pragma("unroll")                                                       \
      for (int nb = 0; nb < 4; ++nb)                                          \
        _Pragma("unroll")                                                     \
        for (int r2 = 0; r2 < 4; ++r2) ACC[nb][r2] *= ar[r2];                 \
    }                                                                         \
    float rs = 0.f;                                                           \
    _Pragma("unroll")                                                         \
    for (int sb = 0; sb < 4; ++sb)                                            \
      _Pragma("unroll")                                                       \
      for (int r2 = 0; r2 < 4; ++r2) {                                        \
        float p = exp2_fast(ST[sb][r2] - M);                                  \
        ST[sb][r2] = p;                                                       \
        rs += p;                                                              \
      }                                                                       \
    rs += __shfl_xor(rs, 16);                                                 \
    rs += __shfl_xor(rs, 32);                                                 \
    LSUM += rs;                                                               \
    _Pragma("unroll")                                                         \
    for (int sb = 0; sb < 4; ++sb) {                                          \
      bf16x4 p4;                                                              \
      p4[0] = (__bf16)ST[sb][0]; p4[1] = (__bf16)ST[sb][1];                   \
      p4[2] = (__bf16)ST[sb][2]; p4[3] = (__bf16)ST[sb][3];                   \
      *(bf16x4*)((PW) + qc * 128 + ((sb * 32 + g * 8) ^ sw)) = p4;            \
    }                                                                         \
  } while (0)

  // one tile's compute against double-buffer at constant byte offset OFF
#define TILE(OFF)                                                             \
  do {                                                                        \
    const char* kb = kbuf + (OFF);                                            \
    const char* vb = vbuf + (OFF);                                            \
    f32x4 stA[4], stB[4];                                                     \
    __builtin_amdgcn_s_setprio(1);                                            \
    _Pragma("unroll")                                                         \
    for (int sb = 0; sb < 4; ++sb) {                                          \
      const int base = (sb * 16 + qc) * 128;                                  \
      bf16x8 k0 = *(const bf16x8*)(kb + base + ((g * 16)      ^ sw));         \
      bf16x8 k1 = *(const bf16x8*)(kb + base + ((64 + g * 16) ^ sw));         \
      f32x4 a; a[0] = 0.f; a[1] = 0.f; a[2] = 0.f; a[3] = 0.f;                \
      f32x4 b; b[0] = 0.f; b[1] = 0.f; b[2] = 0.f; b[3] = 0.f;                \
      a = __builtin_amdgcn_mfma_f32_16x16x32_bf16(k0, qfA[0], a, 0, 0, 0);    \
      b = __builtin_amdgcn_mfma_f32_16x16x32_bf16(k0, qfB[0], b, 0, 0, 0);    \
      a = __builtin_amdgcn_mfma_f32_16x16x32_bf16(k1, qfA[1], a, 0, 0, 0);    \
      b = __builtin_amdgcn_mfma_f32_16x16x32_bf16(k1, qfB[1], b, 0, 0, 0);    \
      stA[sb] = a;                                                            \
      stB[sb] = b;                                                            \
    }                                                                         \
    __builtin_amdgcn_s_setprio(0);                                            \
    SOFTMAX_PACK(stA, mA, lA, accA, pwA);                                     \
    SOFTMAX_PACK(stB, mB, lB, accB, pwB);                                     \
    asm volatile("s_waitcnt lgkmcnt(0)" ::: "memory");                        \
    {                                                                         \
      bf16x8 paA0 = *(const bf16x8*)(pwA + qc * 128 + ((g * 16)      ^ sw));  \
      bf16x8 paA1 = *(const bf16x8*)(pwA + qc * 128 + ((64 + g * 16) ^ sw));  \
      bf16x8 paB0 = *(const bf16x8*)(pwB + qc * 128 + ((g * 16)      ^ sw));  \
      bf16x8 paB1 = *(const bf16x8*)(pwB + qc * 128 + ((64 + g * 16) ^ sw));  \
      __builtin_amdgcn_s_setprio(1);                                          \
      _Pragma("unroll")                                                       \
      for (int nb = 0; nb < 4; ++nb) {                                        \
        const int vbase = (nb * 16 + qc) * 128;                               \
        bf16x8 v0f = *(const bf16x8*)(vb + vbase + ((g * 16)      ^ sw));     \
        bf16x8 v1f = *(const bf16x8*)(vb + vbase + ((64 + g * 16) ^ sw));     \
        accA[nb] = __builtin_amdgcn_mfma_f32_16x16x32_bf16(paA0, v0f, accA[nb], 0, 0, 0); \
        accB[nb] = __builtin_amdgcn_mfma_f32_16x16x32_bf16(paB0, v0f, accB[nb], 0, 0, 0); \
        accA[nb] = __builtin_amdgcn_mfma_f32_16x16x32_bf16(paA1, v1f, accA[nb], 0, 0, 0); \
        accB[nb] = __builtin_amdgcn_mfma_f32_16x16x32_bf16(paB1, v1f, accB[nb], 0, 0, 0); \
      }                                                                       \
      __builtin_amdgcn_s_setprio(0);                                          \
    }                                                                         \
  } while (0)

  STAGE(0, 0);
  __syncthreads();

  for (int t = 0; t < NT; t += 2) {
    if (t + 1 < NT) STAGE(1, t + 1);
    TILE(0);
    __syncthreads();
    if (t + 2 < NT) STAGE(0, t + 2);
    TILE(8192);
    __syncthreads();
  }
#undef STAGE
#undef TILE
#undef SOFTMAX_PACK

  // ---- epilogue: O /= l, store (both halves) ----
#pragma unroll
  for (int h2 = 0; h2 < 2; ++h2) {
    const float lv = (h2 == 0) ? lA : lB;
    f32x4* acc = (h2 == 0) ? accA : accB;
    float linv[4];
#pragma unroll
    for (int r2 = 0; r2 < 4; ++r2) {
      float lr = __shfl(lv, g * 4 + r2);
      linv[r2] = 1.0f / lr;
    }
#pragma unroll
    for (int nb = 0; nb < 4; ++nb)
#pragma unroll
      for (int r2 = 0; r2 < 4; ++r2) {
        const int row = qrow0 + h2 * 16 + g * 4 + r2;
        ob[(size_t)row * rstride + nb * 16 + qc] = acc[nb][r2] * linv[r2];
      }
  }
}

extern "C" void kernel_launch(void* const* d_in, const int* in_sizes, int n_in,
                              void* d_out, int out_size, void* d_ws, size_t ws_size,
                              hipStream_t stream) {
  const float* q = (const float*)d_in[0];
  const float* k = (const float*)d_in[1];
  const float* v = (const float*)d_in[2];
  float* o = (float*)d_out;
  __hip_bfloat16* kw  = (__hip_bfloat16*)d_ws;
  __hip_bfloat16* vtw = kw + KW_ELEMS;

  prep_kv<<<dim3(3072), dim3(256), 0, stream>>>(k, v, kw, vtw);
  sdpa_fwd<<<dim3(512), dim3(256), 0, stream>>>(q, kw, vtw, o);
}